// Round 1
// baseline (716.519 us; speedup 1.0000x reference)
//
#include <hip/hip_runtime.h>

#define B    32
#define N1   1024
#define FIN  128
#define NH   256
#define KP1  512
#define KP2  256
#define NCLS 10
#define MAXD 64

// ---------------- lin: out[M,256] = A[M,KD] @ W[KD,256] ----------------
template<int KD>
__global__ void lin_kernel(const float* __restrict__ A, const float* __restrict__ W,
                           float* __restrict__ out, int M) {
    __shared__ float as[8][KD];
    int m0 = blockIdx.x * 8;
    int f = threadIdx.x;
    for (int i = threadIdx.x; i < 8 * KD; i += 256) {
        int r = i / KD, c = i % KD;
        as[r][c] = A[(size_t)(m0 + r) * KD + c];
    }
    __syncthreads();
    float acc[8] = {};
    for (int k = 0; k < KD; ++k) {
        float w = W[k * NH + f];
        #pragma unroll
        for (int r = 0; r < 8; ++r) acc[r] += as[r][k] * w;
    }
    for (int r = 0; r < 8; ++r) out[(size_t)(m0 + r) * NH + f] = acc[r];
}

// ---------------- CSR build: deterministic (column-ordered) ----------------
__global__ void csr_kernel(const float* __restrict__ adj, int* __restrict__ cnt,
                           int* __restrict__ nbr, float* __restrict__ dgi,
                           float* __restrict__ dia) {
    int row = blockIdx.x;                    // b*N1 + i
    const float* arow = adj + (size_t)row * N1;
    int t = threadIdx.x;                     // 256 threads, 4 cols each
    float4 v4 = ((const float4*)arow)[t];
    int loc[4];
    int c = 0;
    if (v4.x > 0.5f) loc[c++] = t * 4 + 0;
    if (v4.y > 0.5f) loc[c++] = t * 4 + 1;
    if (v4.z > 0.5f) loc[c++] = t * 4 + 2;
    if (v4.w > 0.5f) loc[c++] = t * 4 + 3;
    __shared__ int ps[256];
    ps[t] = c;
    __syncthreads();
    for (int s = 1; s < 256; s <<= 1) {
        int v = (t >= s) ? ps[t - s] : 0;
        __syncthreads();
        ps[t] += v;
        __syncthreads();
    }
    int total = ps[255];
    int off = ps[t] - c;                     // exclusive prefix
    for (int u = 0; u < c; ++u) {
        int p = off + u;
        if (p < MAXD) nbr[(size_t)row * MAXD + p] = loc[u];
    }
    if (t == 0) {
        cnt[row] = min(total, MAXD);
        dgi[row] = rsqrtf((float)total + 1.0f);          // deg of A=adj+I
        dia[row] = total > 0 ? 1.0f / (float)total : 0.0f; // deg of adj
    }
}

// ---------------- stage-1 GCN aggregate (sparse) ----------------
__global__ void gcn1_kernel(const float* __restrict__ t1, const int* __restrict__ cnt,
                            const int* __restrict__ nbr, const float* __restrict__ dgi,
                            const float* __restrict__ b1, float* __restrict__ h1) {
    int row = blockIdx.x;
    int b = row >> 10;
    int i = row & (N1 - 1);
    int bb = b << 10;
    int f = threadIdx.x;
    const float* tb = t1 + (size_t)b * N1 * NH;
    int n = cnt[row];
    __shared__ int lst[MAXD];
    __shared__ float sdg[MAXD];
    for (int e = threadIdx.x; e < n; e += 256) {
        int j = nbr[(size_t)row * MAXD + e];
        lst[e] = j;
        sdg[e] = dgi[bb + j];
    }
    __syncthreads();
    float acc = 0.f;
    for (int e = 0; e < n; ++e)
        acc += sdg[e] * tb[(size_t)lst[e] * NH + f];
    float di = dgi[row];
    float v = di * (acc + di * tb[(size_t)i * NH + f]) + b1[f];
    h1[(size_t)row * NH + f] = fmaxf(v, 0.f);
}

// ---------------- stage-1 info score (sparse) ----------------
__global__ void info1_kernel(const float* __restrict__ h1, const int* __restrict__ cnt,
                             const int* __restrict__ nbr, const float* __restrict__ dia,
                             float* __restrict__ sc) {
    int row = blockIdx.x;
    int b = row >> 10;
    int i = row & (N1 - 1);
    int f = threadIdx.x;
    const float* hb = h1 + (size_t)b * N1 * NH;
    int n = cnt[row];
    __shared__ int lst[MAXD];
    for (int e = threadIdx.x; e < n; e += 256) lst[e] = nbr[(size_t)row * MAXD + e];
    __syncthreads();
    float acc = 0.f;
    for (int e = 0; e < n; ++e) acc += hb[(size_t)lst[e] * NH + f];
    float v = fabsf(hb[(size_t)i * NH + f] - dia[row] * acc);
    __shared__ float red[256];
    red[f] = v;
    __syncthreads();
    for (int s = 128; s > 0; s >>= 1) {
        if (f < s) red[f] += red[f + s];
        __syncthreads();
    }
    if (f == 0) sc[row] = red[0];
}

// ---------------- top-k via bitonic sort (desc, tie: lower index first) ----------------
template<int NS, int KS, int NT>
__global__ void topk_kernel(const float* __restrict__ sc, int* __restrict__ idxo) {
    int b = blockIdx.x;
    __shared__ float s[NS];
    __shared__ int id[NS];
    for (int i = threadIdx.x; i < NS; i += NT) { s[i] = sc[b * NS + i]; id[i] = i; }
    __syncthreads();
    for (int ksz = 2; ksz <= NS; ksz <<= 1) {
        for (int j = ksz >> 1; j > 0; j >>= 1) {
            for (int i = threadIdx.x; i < NS; i += NT) {
                int l = i ^ j;
                if (l > i) {
                    float si = s[i], sl = s[l];
                    int ii = id[i], il = id[l];
                    bool iBeforeL = (si > sl) || (si == sl && ii < il);
                    bool dirDesc = ((i & ksz) == 0);
                    if (dirDesc ? !iBeforeL : iBeforeL) {
                        s[i] = sl; s[l] = si; id[i] = il; id[l] = ii;
                    }
                }
            }
            __syncthreads();
        }
    }
    for (int t = threadIdx.x; t < KS; t += NT) idxo[b * KS + t] = id[t];
}

// ---------------- gather pooled rows + attention dots ----------------
__global__ void gather_att_kernel(const float* __restrict__ h, const int* __restrict__ idx,
                                  const float* __restrict__ att, float* __restrict__ hk,
                                  float* __restrict__ lv, float* __restrict__ rv,
                                  int K, int Nsrc) {
    int g = blockIdx.x;              // b*K + p
    int b = g / K;
    int f = threadIdx.x;
    int src = idx[g];
    float v = h[((size_t)b * Nsrc + src) * NH + f];
    hk[(size_t)g * NH + f] = v;
    __shared__ float r1[256], r2[256];
    r1[f] = v * att[f];
    r2[f] = v * att[NH + f];
    __syncthreads();
    for (int s = 128; s > 0; s >>= 1) {
        if (f < s) { r1[f] += r1[f + s]; r2[f] += r2[f + s]; }
        __syncthreads();
    }
    if (f == 0) { lv[g] = r1[0]; rv[g] = r2[0]; }
}

// ---------------- structure-learning logits + row softmax ----------------
template<int KP, int ASTR>
__global__ void pool_softmax_kernel(const float* __restrict__ adjsrc, const int* __restrict__ idx,
                                    const float* __restrict__ lv, const float* __restrict__ rv,
                                    float* __restrict__ aout) {
    int g = blockIdx.x;              // b*KP + p
    int b = g / KP, p = g % KP;
    __shared__ int sid[KP];
    __shared__ float sr[KP];
    for (int i = threadIdx.x; i < KP; i += 256) { sid[i] = idx[b * KP + i]; sr[i] = rv[b * KP + i]; }
    __syncthreads();
    int ip = sid[p];
    float lp = lv[g];
    const float* arow = adjsrc + ((size_t)b * ASTR + ip) * ASTR;
    float lo[KP / 256];
    float mx = -1e30f;
    #pragma unroll
    for (int t = 0; t < KP / 256; ++t) {
        int q = threadIdx.x + t * 256;
        float v = lp + sr[q] + arow[sid[q]];   // LAMB = 1.0
        lo[t] = v;
        mx = fmaxf(mx, v);
    }
    __shared__ float red[256];
    red[threadIdx.x] = mx;
    __syncthreads();
    for (int s = 128; s > 0; s >>= 1) {
        if (threadIdx.x < s) red[threadIdx.x] = fmaxf(red[threadIdx.x], red[threadIdx.x + s]);
        __syncthreads();
    }
    mx = red[0];
    __syncthreads();
    float sum = 0.f;
    #pragma unroll
    for (int t = 0; t < KP / 256; ++t) { lo[t] = expf(lo[t] - mx); sum += lo[t]; }
    red[threadIdx.x] = sum;
    __syncthreads();
    for (int s = 128; s > 0; s >>= 1) {
        if (threadIdx.x < s) red[threadIdx.x] += red[threadIdx.x + s];
        __syncthreads();
    }
    float inv = 1.0f / red[0];
    #pragma unroll
    for (int t = 0; t < KP / 256; ++t) {
        int q = threadIdx.x + t * 256;
        aout[(size_t)g * KP + q] = lo[t] * inv;
    }
}

// ---------------- readout: rout[b, 0:256]=relu(max), [256:512]=relu(mean) ----------------
template<int NROWS, bool INIT>
__global__ void readout_kernel(const float* __restrict__ h, float* __restrict__ rout) {
    int b = blockIdx.x;
    int f = threadIdx.x;
    const float* hb = h + (size_t)b * NROWS * NH;
    float mx = -1e30f, sm = 0.f;
    for (int p = 0; p < NROWS; ++p) {
        float v = hb[(size_t)p * NH + f];
        mx = fmaxf(mx, v);
        sm += v;
    }
    float rm = fmaxf(mx, 0.f);
    float ra = fmaxf(sm * (1.0f / NROWS), 0.f);
    if (INIT) {
        rout[b * 512 + f] = rm;
        rout[b * 512 + NH + f] = ra;
    } else {
        rout[b * 512 + f] += rm;
        rout[b * 512 + NH + f] += ra;
    }
}

// ---------------- dense GCN aggregate: h = relu(0.5*(a@t + t) + bias) ----------------
template<int KP>
__global__ void gcn_dense_kernel(const float* __restrict__ a, const float* __restrict__ t,
                                 const float* __restrict__ bias, float* __restrict__ h) {
    constexpr int BPB = KP / 16;
    int b = blockIdx.x / BPB;
    int p0 = (blockIdx.x % BPB) * 16;
    int f = threadIdx.x;
    const float* ab = a + (size_t)b * KP * KP;
    const float* tb = t + (size_t)b * KP * NH;
    float acc[16] = {};
    __shared__ float sa[16][64];
    for (int q0 = 0; q0 < KP; q0 += 64) {
        for (int i = threadIdx.x; i < 16 * 64; i += 256) {
            int r = i >> 6, c = i & 63;
            sa[r][c] = ab[(size_t)(p0 + r) * KP + q0 + c];
        }
        __syncthreads();
        for (int q = 0; q < 64; ++q) {
            float tv = tb[(size_t)(q0 + q) * NH + f];
            #pragma unroll
            for (int r = 0; r < 16; ++r) acc[r] += sa[r][q] * tv;
        }
        __syncthreads();
    }
    float bf = bias[f];
    for (int r = 0; r < 16; ++r) {
        size_t o = (size_t)(p0 + r) * NH + f;
        h[(size_t)b * KP * NH + o] = fmaxf(0.5f * (acc[r] + tb[o]) + bf, 0.f);
    }
}

// ---------------- dense info score: sc = || h - a@h ||_1 (dinv==1) ----------------
template<int KP>
__global__ void info_dense_kernel(const float* __restrict__ a, const float* __restrict__ h,
                                  float* __restrict__ sc) {
    constexpr int BPB = KP / 16;
    int b = blockIdx.x / BPB;
    int p0 = (blockIdx.x % BPB) * 16;
    int f = threadIdx.x;
    const float* ab = a + (size_t)b * KP * KP;
    const float* hb = h + (size_t)b * KP * NH;
    float acc[16] = {};
    __shared__ float sa[16][64];
    for (int q0 = 0; q0 < KP; q0 += 64) {
        for (int i = threadIdx.x; i < 16 * 64; i += 256) {
            int r = i >> 6, c = i & 63;
            sa[r][c] = ab[(size_t)(p0 + r) * KP + q0 + c];
        }
        __syncthreads();
        for (int q = 0; q < 64; ++q) {
            float hv = hb[(size_t)(q0 + q) * NH + f];
            #pragma unroll
            for (int r = 0; r < 16; ++r) acc[r] += sa[r][q] * hv;
        }
        __syncthreads();
    }
    __shared__ float red[256];
    for (int r = 0; r < 16; ++r) {
        red[f] = fabsf(hb[(size_t)(p0 + r) * NH + f] - acc[r]);
        __syncthreads();
        for (int s = 128; s > 0; s >>= 1) {
            if (f < s) red[f] += red[f + s];
            __syncthreads();
        }
        if (f == 0) sc[b * KP + p0 + r] = red[0];
        __syncthreads();
    }
}

// ---------------- final linear ----------------
__global__ void final_kernel(const float* __restrict__ rout, const float* __restrict__ Wlin,
                             const float* __restrict__ blin, float* __restrict__ out) {
    int b = blockIdx.x;
    int c = threadIdx.x;
    if (c < NCLS) {
        float acc = blin[c];
        for (int fidx = 0; fidx < 512; ++fidx)
            acc += rout[b * 512 + fidx] * Wlin[fidx * NCLS + c];
        out[b * NCLS + c] = acc;
    }
}

extern "C" void kernel_launch(void* const* d_in, const int* in_sizes, int n_in,
                              void* d_out, int out_size, void* d_ws, size_t ws_size,
                              hipStream_t stream) {
    const float* x    = (const float*)d_in[0];
    const float* adj  = (const float*)d_in[1];
    const float* W1   = (const float*)d_in[2];
    const float* b1   = (const float*)d_in[3];
    const float* W2   = (const float*)d_in[4];
    const float* b2   = (const float*)d_in[5];
    const float* W3   = (const float*)d_in[6];
    const float* b3   = (const float*)d_in[7];
    const float* att1 = (const float*)d_in[8];
    const float* att2 = (const float*)d_in[9];
    const float* Wlin = (const float*)d_in[10];
    const float* blin = (const float*)d_in[11];
    float* out = (float*)d_out;

    float* fws = (float*)d_ws;
    float* t1  = fws;                        // B*N1*NH = 8388608
    float* h1  = t1 + 8388608;               // 8388608
    float* hk  = h1 + 8388608;               // B*KP1*NH = 4194304
    float* t3  = hk + 4194304;               // B*KP2*NH = 2097152
    float* h3  = t3 + 2097152;               // 2097152
    float* dgi = h3 + 2097152;               // B*N1
    float* dia = dgi + 32768;                // B*N1
    float* sc  = dia + 32768;                // B*N1
    float* lv  = sc + 32768;                 // B*KP1
    float* rv  = lv + 16384;                 // B*KP1
    float* rout = rv + 16384;                // B*512
    int* cnt  = (int*)(rout + 16384);        // B*N1
    int* nbr  = cnt + 32768;                 // B*N1*MAXD
    int* idx1 = nbr + 32768 * MAXD;          // B*KP1
    int* idx2 = idx1 + 16384;                // B*KP2
    // aliases (lifetime-disjoint reuse)
    float* a1  = t1;                         // B*KP1*KP1 = 8388608
    float* t2  = h1;                         // B*KP1*NH
    float* h2  = h1 + 4194304;               // B*KP1*NH
    float* h2k = hk;                         // B*KP2*NH
    float* a2  = hk + 2097152;               // B*KP2*KP2

    // stage 1
    lin_kernel<FIN><<<4096, 256, 0, stream>>>(x, W1, t1, B * N1);
    csr_kernel<<<B * N1, 256, 0, stream>>>(adj, cnt, nbr, dgi, dia);
    gcn1_kernel<<<B * N1, 256, 0, stream>>>(t1, cnt, nbr, dgi, b1, h1);
    info1_kernel<<<B * N1, 256, 0, stream>>>(h1, cnt, nbr, dia, sc);
    topk_kernel<N1, KP1, 512><<<B, 512, 0, stream>>>(sc, idx1);
    gather_att_kernel<<<B * KP1, 256, 0, stream>>>(h1, idx1, att1, hk, lv, rv, KP1, N1);
    pool_softmax_kernel<KP1, N1><<<B * KP1, 256, 0, stream>>>(adj, idx1, lv, rv, a1);
    readout_kernel<KP1, true><<<B, 256, 0, stream>>>(hk, rout);

    // stage 2
    lin_kernel<NH><<<2048, 256, 0, stream>>>(hk, W2, t2, B * KP1);
    gcn_dense_kernel<KP1><<<B * (KP1 / 16), 256, 0, stream>>>(a1, t2, b2, h2);
    info_dense_kernel<KP1><<<B * (KP1 / 16), 256, 0, stream>>>(a1, h2, sc);
    topk_kernel<KP1, KP2, 256><<<B, 256, 0, stream>>>(sc, idx2);
    gather_att_kernel<<<B * KP2, 256, 0, stream>>>(h2, idx2, att2, h2k, lv, rv, KP2, KP1);
    pool_softmax_kernel<KP2, KP1><<<B * KP2, 256, 0, stream>>>(a1, idx2, lv, rv, a2);
    readout_kernel<KP2, false><<<B, 256, 0, stream>>>(h2k, rout);

    // stage 3
    lin_kernel<NH><<<1024, 256, 0, stream>>>(h2k, W3, t3, B * KP2);
    gcn_dense_kernel<KP2><<<B * (KP2 / 16), 256, 0, stream>>>(a2, t3, b3, h3);
    readout_kernel<KP2, false><<<B, 256, 0, stream>>>(h3, rout);

    // classifier
    final_kernel<<<B, 64, 0, stream>>>(rout, Wlin, blin, out);
}

// Round 2
// 526.685 us; speedup vs baseline: 1.3604x; 1.3604x over previous
//
#include <hip/hip_runtime.h>

#define B    32
#define N1   1024
#define FIN  128
#define NH   256
#define KP1  512
#define KP2  256
#define NCLS 10
#define MAXD 64
#define E1   1.7182818284590452f   // e^LAMB - 1, LAMB = 1.0

// ---------------- lin: out[M,256] = A[M,KD] @ W[KD,256], 16 rows/block ----------------
template<int KD>
__global__ void lin_kernel(const float* __restrict__ A, const float* __restrict__ W,
                           float* __restrict__ out, int M) {
    __shared__ float as[16][KD];
    int m0 = blockIdx.x * 16;
    int f = threadIdx.x;
    for (int i = threadIdx.x; i < 16 * KD; i += 256)
        as[i / KD][i % KD] = A[(size_t)m0 * KD + i];
    __syncthreads();
    float acc[16] = {};
    for (int k = 0; k < KD; ++k) {
        float w = W[k * NH + f];
        #pragma unroll
        for (int r = 0; r < 16; ++r) acc[r] += as[r][k] * w;
    }
    for (int r = 0; r < 16; ++r) out[(size_t)(m0 + r) * NH + f] = acc[r];
}

// ---------------- CSR build: deterministic (column-ordered) ----------------
__global__ void csr_kernel(const float* __restrict__ adj, int* __restrict__ cnt,
                           int* __restrict__ nbr, float* __restrict__ dgi,
                           float* __restrict__ dia) {
    int row = blockIdx.x;                    // b*N1 + i
    const float* arow = adj + (size_t)row * N1;
    int t = threadIdx.x;                     // 256 threads, 4 cols each
    float4 v4 = ((const float4*)arow)[t];
    int loc[4];
    int c = 0;
    if (v4.x > 0.5f) loc[c++] = t * 4 + 0;
    if (v4.y > 0.5f) loc[c++] = t * 4 + 1;
    if (v4.z > 0.5f) loc[c++] = t * 4 + 2;
    if (v4.w > 0.5f) loc[c++] = t * 4 + 3;
    __shared__ int ps[256];
    ps[t] = c;
    __syncthreads();
    for (int s = 1; s < 256; s <<= 1) {
        int v = (t >= s) ? ps[t - s] : 0;
        __syncthreads();
        ps[t] += v;
        __syncthreads();
    }
    int total = ps[255];
    int off = ps[t] - c;                     // exclusive prefix
    for (int u = 0; u < c; ++u) {
        int p = off + u;
        if (p < MAXD) nbr[(size_t)row * MAXD + p] = loc[u];
    }
    if (t == 0) {
        cnt[row] = min(total, MAXD);
        dgi[row] = rsqrtf((float)total + 1.0f);            // deg of A=adj+I
        dia[row] = total > 0 ? 1.0f / (float)total : 0.0f; // deg of adj
    }
}

// ---------------- stage-1 GCN aggregate (sparse) ----------------
__global__ void gcn1_kernel(const float* __restrict__ t1, const int* __restrict__ cnt,
                            const int* __restrict__ nbr, const float* __restrict__ dgi,
                            const float* __restrict__ b1, float* __restrict__ h1) {
    int row = blockIdx.x;
    int b = row >> 10;
    int i = row & (N1 - 1);
    int bb = b << 10;
    int f = threadIdx.x;
    const float* tb = t1 + (size_t)b * N1 * NH;
    int n = cnt[row];
    __shared__ int lst[MAXD];
    __shared__ float sdg[MAXD];
    if (threadIdx.x < n) {
        int j = nbr[(size_t)row * MAXD + threadIdx.x];
        lst[threadIdx.x] = j;
        sdg[threadIdx.x] = dgi[bb + j];
    }
    __syncthreads();
    float acc = 0.f;
    for (int e = 0; e < n; ++e)
        acc += sdg[e] * tb[(size_t)lst[e] * NH + f];
    float di = dgi[row];
    float v = di * (acc + di * tb[(size_t)i * NH + f]) + b1[f];
    h1[(size_t)row * NH + f] = fmaxf(v, 0.f);
}

// ---------------- stage-1 info score (sparse) ----------------
__global__ void info1_kernel(const float* __restrict__ h1, const int* __restrict__ cnt,
                             const int* __restrict__ nbr, const float* __restrict__ dia,
                             float* __restrict__ sc) {
    int row = blockIdx.x;
    int b = row >> 10;
    int i = row & (N1 - 1);
    int f = threadIdx.x;
    const float* hb = h1 + (size_t)b * N1 * NH;
    int n = cnt[row];
    __shared__ int lst[MAXD];
    if (threadIdx.x < n) lst[threadIdx.x] = nbr[(size_t)row * MAXD + threadIdx.x];
    __syncthreads();
    float acc = 0.f;
    for (int e = 0; e < n; ++e) acc += hb[(size_t)lst[e] * NH + f];
    float v = fabsf(hb[(size_t)i * NH + f] - dia[row] * acc);
    __shared__ float red[256];
    red[f] = v;
    __syncthreads();
    for (int s = 128; s > 0; s >>= 1) {
        if (f < s) red[f] += red[f + s];
        __syncthreads();
    }
    if (f == 0) sc[row] = red[0];
}

// ---------------- top-k via bitonic sort (desc, tie: lower index first) ----------------
template<int NS, int KS, int NT>
__global__ void topk_kernel(const float* __restrict__ sc, int* __restrict__ idxo) {
    int b = blockIdx.x;
    __shared__ float s[NS];
    __shared__ int id[NS];
    for (int i = threadIdx.x; i < NS; i += NT) { s[i] = sc[b * NS + i]; id[i] = i; }
    __syncthreads();
    for (int ksz = 2; ksz <= NS; ksz <<= 1) {
        for (int j = ksz >> 1; j > 0; j >>= 1) {
            for (int i = threadIdx.x; i < NS; i += NT) {
                int l = i ^ j;
                if (l > i) {
                    float si = s[i], sl = s[l];
                    int ii = id[i], il = id[l];
                    bool iBeforeL = (si > sl) || (si == sl && ii < il);
                    bool dirDesc = ((i & ksz) == 0);
                    if (dirDesc ? !iBeforeL : iBeforeL) {
                        s[i] = sl; s[l] = si; id[i] = il; id[l] = ii;
                    }
                }
            }
            __syncthreads();
        }
    }
    for (int t = threadIdx.x; t < KS; t += NT) idxo[b * KS + t] = id[t];
}

// ---------------- gather pooled rows + attention dots ----------------
__global__ void gather_att_kernel(const float* __restrict__ h, const int* __restrict__ idx,
                                  const float* __restrict__ att, float* __restrict__ hk,
                                  float* __restrict__ lv, float* __restrict__ rv,
                                  int K, int Nsrc) {
    int g = blockIdx.x;              // b*K + p
    int b = g / K;
    int f = threadIdx.x;
    int src = idx[g];
    float v = h[((size_t)b * Nsrc + src) * NH + f];
    hk[(size_t)g * NH + f] = v;
    __shared__ float r1[256], r2[256];
    r1[f] = v * att[f];
    r2[f] = v * att[NH + f];
    __syncthreads();
    for (int s = 128; s > 0; s >>= 1) {
        if (f < s) { r1[f] += r1[f + s]; r2[f] += r2[f + s]; }
        __syncthreads();
    }
    if (f == 0) { lv[g] = r1[0]; rv[g] = r2[0]; }
}

// ---------------- v = exp(r - rowmax), V = sum v (per batch) ----------------
__global__ void vexp_kernel(const float* __restrict__ rv, float* __restrict__ v1,
                            float* __restrict__ V1) {
    int b = blockIdx.x;
    int t = threadIdx.x;             // 512
    __shared__ float red[512];
    float r = rv[b * KP1 + t];
    red[t] = r;
    __syncthreads();
    for (int s = 256; s > 0; s >>= 1) {
        if (t < s) red[t] = fmaxf(red[t], red[t + s]);
        __syncthreads();
    }
    float mx = red[0];
    __syncthreads();
    float v = expf(r - mx);
    v1[b * KP1 + t] = v;
    red[t] = v;
    __syncthreads();
    for (int s = 256; s > 0; s >>= 1) {
        if (t < s) red[t] += red[t + s];
        __syncthreads();
    }
    if (t == 0) V1[b] = red[0];
}

// ---------------- position maps ----------------
__global__ void fillneg_kernel(int* __restrict__ p, int n) {
    int i = blockIdx.x * 256 + threadIdx.x;
    if (i < n) p[i] = -1;
}
__global__ void scatter_pos_kernel(const int* __restrict__ idx, int* __restrict__ pos) {
    int g = blockIdx.x * 256 + threadIdx.x;   // b*KP1 + p
    int b = g / KP1, p = g % KP1;
    pos[b * N1 + idx[g]] = p;
}

// ---------------- induced-subgraph CSR on idx1 + Z1 = V + E1*sum_nbr(v) ----------------
__global__ void knbr_kernel(const int* __restrict__ idx1, const int* __restrict__ cnt,
                            const int* __restrict__ nbr, const int* __restrict__ pos1,
                            const float* __restrict__ v1, const float* __restrict__ V1,
                            int* __restrict__ knbr, int* __restrict__ kcnt,
                            float* __restrict__ Z1) {
    int g = blockIdx.x;              // b*KP1 + p
    int b = g / KP1;
    int lane = threadIdx.x;          // 64 = one wave
    int ip = idx1[g];
    int n = cnt[b * N1 + ip];
    int q = -1;
    if (lane < n) {
        int j = nbr[(size_t)(b * N1 + ip) * MAXD + lane];
        q = pos1[b * N1 + j];
    }
    bool kept = q >= 0;
    unsigned long long mask = __ballot(kept);
    int off = __popcll(mask & ((1ull << lane) - 1ull));
    if (kept) knbr[(size_t)g * MAXD + off] = q;
    float s = kept ? v1[b * KP1 + q] : 0.f;
    for (int o = 32; o > 0; o >>= 1) s += __shfl_down(s, o);
    if (lane == 0) { kcnt[g] = __popcll(mask); Z1[g] = V1[b] + E1 * s; }
}

// ---------------- per-batch weighted column sum (partials over 8 chunks) ----------------
__global__ void wsum_kernel(const float* __restrict__ X, const float* __restrict__ v1,
                            float* __restrict__ wp) {
    int blk = blockIdx.x;            // b*8 + c
    int b = blk >> 3, c = blk & 7;
    int f = threadIdx.x;
    float acc = 0.f;
    for (int q = c * 64; q < c * 64 + 64; ++q)
        acc += v1[b * KP1 + q] * X[(size_t)(b * KP1 + q) * NH + f];
    wp[(size_t)blk * NH + f] = acc;
}

// ---------------- stage-2 GCN via factorized a1 ----------------
__global__ void gcn2_kernel(const float* __restrict__ t2, const float* __restrict__ wp,
                            const float* __restrict__ v1, const float* __restrict__ Z1,
                            const int* __restrict__ knbr, const int* __restrict__ kcnt,
                            const float* __restrict__ b2, float* __restrict__ h2) {
    int g = blockIdx.x;              // b*KP1 + p
    int b = g / KP1;
    int f = threadIdx.x;
    __shared__ int lst[MAXD];
    __shared__ float wv[MAXD];
    int n = kcnt[g];
    if (threadIdx.x < n) {
        int q = knbr[(size_t)g * MAXD + threadIdx.x];
        lst[threadIdx.x] = q;
        wv[threadIdx.x] = v1[b * KP1 + q];
    }
    __syncthreads();
    float acc = 0.f;
    for (int e = 0; e < n; ++e)
        acc += wv[e] * t2[(size_t)(b * KP1 + lst[e]) * NH + f];
    float w = 0.f;
    #pragma unroll
    for (int c = 0; c < 8; ++c) w += wp[(size_t)(b * 8 + c) * NH + f];
    float agg = (w + E1 * acc) / Z1[g];
    float tv = t2[(size_t)g * NH + f];
    h2[(size_t)g * NH + f] = fmaxf(0.5f * (agg + tv) + b2[f], 0.f);
}

// ---------------- stage-2 info score via factorized a1 ----------------
__global__ void info2_kernel(const float* __restrict__ h2, const float* __restrict__ wp,
                             const float* __restrict__ v1, const float* __restrict__ Z1,
                             const int* __restrict__ knbr, const int* __restrict__ kcnt,
                             float* __restrict__ sc) {
    int g = blockIdx.x;              // b*KP1 + p
    int b = g / KP1;
    int f = threadIdx.x;
    __shared__ int lst[MAXD];
    __shared__ float wv[MAXD];
    int n = kcnt[g];
    if (threadIdx.x < n) {
        int q = knbr[(size_t)g * MAXD + threadIdx.x];
        lst[threadIdx.x] = q;
        wv[threadIdx.x] = v1[b * KP1 + q];
    }
    __syncthreads();
    float acc = 0.f;
    for (int e = 0; e < n; ++e)
        acc += wv[e] * h2[(size_t)(b * KP1 + lst[e]) * NH + f];
    float w = 0.f;
    #pragma unroll
    for (int c = 0; c < 8; ++c) w += wp[(size_t)(b * 8 + c) * NH + f];
    float agg = (w + E1 * acc) / Z1[g];
    float val = fabsf(h2[(size_t)g * NH + f] - agg);
    __shared__ float red[256];
    red[f] = val;
    __syncthreads();
    for (int s = 128; s > 0; s >>= 1) {
        if (f < s) red[f] += red[f + s];
        __syncthreads();
    }
    if (f == 0) sc[g] = red[0];
}

// ---------------- materialize a2 = softmax(r2_q + a1k[p,q]) ----------------
__global__ void a2_kernel(const int* __restrict__ idx2, const float* __restrict__ rv,
                          const float* __restrict__ v1, const float* __restrict__ Z1,
                          const int* __restrict__ knbr, const int* __restrict__ kcnt,
                          float* __restrict__ a2) {
    int g = blockIdx.x;              // b*KP2 + p
    int b = g / KP2;
    int q = threadIdx.x;             // 256
    int p2 = idx2[g];                // position in [0,KP1)
    int gp = b * KP1 + p2;
    __shared__ unsigned char flag[KP1];
    flag[q] = 0; flag[q + 256] = 0;
    __syncthreads();
    int n = kcnt[gp];
    if (q < n) flag[knbr[(size_t)gp * MAXD + q]] = 1;
    __syncthreads();
    int q2 = idx2[b * KP2 + q];
    float a1k = v1[b * KP1 + q2] * (flag[q2] ? (1.f + E1) : 1.f) / Z1[gp];
    float z = rv[b * KP2 + q] + a1k;       // l_p cancels in softmax
    __shared__ float red[256];
    red[q] = z;
    __syncthreads();
    for (int s = 128; s > 0; s >>= 1) {
        if (q < s) red[q] = fmaxf(red[q], red[q + s]);
        __syncthreads();
    }
    float mx = red[0];
    __syncthreads();
    float e = expf(z - mx);
    red[q] = e;
    __syncthreads();
    for (int s = 128; s > 0; s >>= 1) {
        if (q < s) red[q] += red[q + s];
        __syncthreads();
    }
    a2[(size_t)g * KP2 + q] = e / red[0];
}

// ---------------- readout: rout[b, 0:256]=relu(max), [256:512]=relu(mean) ----------------
template<int NROWS, bool INIT>
__global__ void readout_kernel(const float* __restrict__ h, float* __restrict__ rout) {
    int b = blockIdx.x;
    int f = threadIdx.x;
    const float* hb = h + (size_t)b * NROWS * NH;
    float mx = -1e30f, sm = 0.f;
    for (int p = 0; p < NROWS; ++p) {
        float v = hb[(size_t)p * NH + f];
        mx = fmaxf(mx, v);
        sm += v;
    }
    float rm = fmaxf(mx, 0.f);
    float ra = fmaxf(sm * (1.0f / NROWS), 0.f);
    if (INIT) {
        rout[b * 512 + f] = rm;
        rout[b * 512 + NH + f] = ra;
    } else {
        rout[b * 512 + f] += rm;
        rout[b * 512 + NH + f] += ra;
    }
}

// ---------------- dense GCN aggregate: h = relu(0.5*(a@t + t) + bias) ----------------
template<int KP>
__global__ void gcn_dense_kernel(const float* __restrict__ a, const float* __restrict__ t,
                                 const float* __restrict__ bias, float* __restrict__ h) {
    constexpr int BPB = KP / 16;
    int b = blockIdx.x / BPB;
    int p0 = (blockIdx.x % BPB) * 16;
    int f = threadIdx.x;
    const float* ab = a + (size_t)b * KP * KP;
    const float* tb = t + (size_t)b * KP * NH;
    float acc[16] = {};
    __shared__ float sa[16][64];
    for (int q0 = 0; q0 < KP; q0 += 64) {
        for (int i = threadIdx.x; i < 16 * 64; i += 256) {
            int r = i >> 6, c = i & 63;
            sa[r][c] = ab[(size_t)(p0 + r) * KP + q0 + c];
        }
        __syncthreads();
        for (int q = 0; q < 64; ++q) {
            float tv = tb[(size_t)(q0 + q) * NH + f];
            #pragma unroll
            for (int r = 0; r < 16; ++r) acc[r] += sa[r][q] * tv;
        }
        __syncthreads();
    }
    float bf = bias[f];
    for (int r = 0; r < 16; ++r) {
        size_t o = (size_t)(p0 + r) * NH + f;
        h[(size_t)b * KP * NH + o] = fmaxf(0.5f * (acc[r] + tb[o]) + bf, 0.f);
    }
}

// ---------------- final linear ----------------
__global__ void final_kernel(const float* __restrict__ rout, const float* __restrict__ Wlin,
                             const float* __restrict__ blin, float* __restrict__ out) {
    int b = blockIdx.x;
    int c = threadIdx.x;
    if (c < NCLS) {
        float acc = blin[c];
        for (int fidx = 0; fidx < 512; ++fidx)
            acc += rout[b * 512 + fidx] * Wlin[fidx * NCLS + c];
        out[b * NCLS + c] = acc;
    }
}

extern "C" void kernel_launch(void* const* d_in, const int* in_sizes, int n_in,
                              void* d_out, int out_size, void* d_ws, size_t ws_size,
                              hipStream_t stream) {
    const float* x    = (const float*)d_in[0];
    const float* adj  = (const float*)d_in[1];
    const float* W1   = (const float*)d_in[2];
    const float* b1   = (const float*)d_in[3];
    const float* W2   = (const float*)d_in[4];
    const float* b2   = (const float*)d_in[5];
    const float* W3   = (const float*)d_in[6];
    const float* b3   = (const float*)d_in[7];
    const float* att1 = (const float*)d_in[8];
    const float* att2 = (const float*)d_in[9];
    const float* Wlin = (const float*)d_in[10];
    const float* blin = (const float*)d_in[11];
    float* out = (float*)d_out;

    float* fws = (float*)d_ws;
    float* t1  = fws;                        // 8,388,608 floats
    float* h1  = t1 + 8388608;               // 8,388,608
    float* hk  = h1 + 8388608;               // 4,194,304
    float* dgi = hk + 4194304;               // 32768
    float* dia = dgi + 32768;
    float* sc  = dia + 32768;
    float* lv  = sc + 32768;                 // 16384
    float* rv  = lv + 16384;                 // 16384
    float* rout = rv + 16384;                // 16384
    float* v1  = rout + 16384;               // 16384
    float* V1  = v1 + 16384;                 // 64 (padded)
    float* Z1  = V1 + 64;                    // 16384
    float* wp  = Z1 + 16384;                 // 32*8*256 = 65536
    int* cnt  = (int*)(wp + 65536);          // 32768
    int* nbr  = cnt + 32768;                 // 32768*64 = 2,097,152
    int* idx1 = nbr + 32768 * MAXD;          // 16384
    int* idx2 = idx1 + 16384;                // 8192
    int* pos1 = idx2 + 8192;                 // 32768
    // aliases (lifetime-disjoint reuse)
    float* t2   = h1;                        // stage-2 XW   [B*KP1*NH]
    float* h2   = h1 + 4194304;              // stage-2 hidden
    float* h2k  = hk;                        // stage-2 pooled rows
    float* a2   = t1;                        // [B*KP2*KP2] = 2,097,152 (t1 dead after gcn1)
    float* t3   = t1 + 2097152;              // 2,097,152
    float* h3   = t1 + 4194304;              // 2,097,152
    int*   knbr = (int*)(t1 + 6291456);      // 16384*64 = 1,048,576 ints
    int*   kcnt = knbr + 16384 * MAXD;       // 16384

    // ---- stage 1 (sparse binary graph) ----
    lin_kernel<FIN><<<2048, 256, 0, stream>>>(x, W1, t1, B * N1);
    csr_kernel<<<B * N1, 256, 0, stream>>>(adj, cnt, nbr, dgi, dia);
    gcn1_kernel<<<B * N1, 256, 0, stream>>>(t1, cnt, nbr, dgi, b1, h1);
    info1_kernel<<<B * N1, 256, 0, stream>>>(h1, cnt, nbr, dia, sc);
    topk_kernel<N1, KP1, 512><<<B, 512, 0, stream>>>(sc, idx1);
    gather_att_kernel<<<B * KP1, 256, 0, stream>>>(h1, idx1, att1, hk, lv, rv, KP1, N1);
    readout_kernel<KP1, true><<<B, 256, 0, stream>>>(hk, rout);

    // ---- pool-1 factorization: a1[p,q] = v_q*(1+E1*adjk)/Z_p ----
    vexp_kernel<<<B, 512, 0, stream>>>(rv, v1, V1);
    fillneg_kernel<<<128, 256, 0, stream>>>(pos1, B * N1);
    scatter_pos_kernel<<<64, 256, 0, stream>>>(idx1, pos1);
    knbr_kernel<<<B * KP1, 64, 0, stream>>>(idx1, cnt, nbr, pos1, v1, V1, knbr, kcnt, Z1);

    // ---- stage 2 (factorized a1) ----
    lin_kernel<NH><<<1024, 256, 0, stream>>>(hk, W2, t2, B * KP1);
    wsum_kernel<<<B * 8, 256, 0, stream>>>(t2, v1, wp);
    gcn2_kernel<<<B * KP1, 256, 0, stream>>>(t2, wp, v1, Z1, knbr, kcnt, b2, h2);
    wsum_kernel<<<B * 8, 256, 0, stream>>>(h2, v1, wp);
    info2_kernel<<<B * KP1, 256, 0, stream>>>(h2, wp, v1, Z1, knbr, kcnt, sc);
    topk_kernel<KP1, KP2, 256><<<B, 256, 0, stream>>>(sc, idx2);
    gather_att_kernel<<<B * KP2, 256, 0, stream>>>(h2, idx2, att2, h2k, lv, rv, KP2, KP1);
    readout_kernel<KP2, false><<<B, 256, 0, stream>>>(h2k, rout);
    a2_kernel<<<B * KP2, 256, 0, stream>>>(idx2, rv, v1, Z1, knbr, kcnt, a2);

    // ---- stage 3 (dense a2, small) ----
    lin_kernel<NH><<<512, 256, 0, stream>>>(h2k, W3, t3, B * KP2);
    gcn_dense_kernel<KP2><<<B * (KP2 / 16), 256, 0, stream>>>(a2, t3, b3, h3);
    readout_kernel<KP2, false><<<B, 256, 0, stream>>>(h3, rout);

    // ---- classifier ----
    final_kernel<<<B, 64, 0, stream>>>(rout, Wlin, blin, out);
}